// Round 13
// baseline (127.610 us; speedup 1.0000x reference)
//
#include <hip/hip_runtime.h>

#define BB 8
#define SS 2048
#define DD 128
#define ROWS 16            // q rows per block
#define NW 4               // waves per block (256 threads)
#define CTW 32             // col-tiles (of 16) per wave -> 512 cols/wave

typedef short bf16x8 __attribute__((ext_vector_type(8)));
typedef float f32x4 __attribute__((ext_vector_type(4)));

template <int I> struct IC { static constexpr int value = I; };
template <int I, int N, typename F>
__device__ __forceinline__ void sfor(F&& f) {
  if constexpr (I < N) { f(IC<I>{}); sfor<I + 1, N>((F&&)f); }
}

__device__ __forceinline__ short f2bf(float x) {
  return __builtin_bit_cast(short, (__bf16)x);
}
__device__ __forceinline__ unsigned pk2(float a, float b) {
  return (unsigned)(unsigned short)f2bf(a) |
         ((unsigned)(unsigned short)f2bf(b) << 16);
}

// async DMA one 4KB tile: 4x (64 lanes x 16B), LDS dest = uniform base + lane*16
__device__ __forceinline__ void stage_tile(const short* g, short* l) {
#pragma unroll
  for (int s = 0; s < 4; ++s) {
    __builtin_amdgcn_global_load_lds(
        (const __attribute__((address_space(1))) void*)(g + (s << 9)),
        (__attribute__((address_space(3))) void*)(l + (s << 9)), 16, 0, 0);
  }
}

// ---- prep: Khi = bf16(K) in MFMA B-fragment order; READ-COALESCED ----
__global__ __launch_bounds__(256)
void ksplit(const float* __restrict__ K, short* __restrict__ Khi) {
  const int lin = blockIdx.x * 256 + threadIdx.x;    // 262144 chunks of 8
  const int r   = lin >> 4;                          // global K row (b*2048+row)
  const int c8  = lin & 15;                          // which 8-float chunk
  const float4 v0 = *(const float4*)(K + (size_t)lin * 8);
  const float4 v1 = *(const float4*)(K + (size_t)lin * 8 + 4);
  bf16x8 h;
  h[0] = f2bf(v0.x); h[1] = f2bf(v0.y); h[2] = f2bf(v0.z); h[3] = f2bf(v0.w);
  h[4] = f2bf(v1.x); h[5] = f2bf(v1.y); h[6] = f2bf(v1.z); h[7] = f2bf(v1.w);
  const int bct  = r >> 4;                           // b*128 + ct
  const int m16  = r & 15;
  const int s    = c8 >> 2;
  const int quad = c8 & 3;
  const size_t out = ((((size_t)bct * 4 + s) * 64) + quad * 16 + m16) * 8;
  *(bf16x8*)(Khi + out) = h;
}

// ---- fused entmax attention: R8 algorithm in 4-wave blocks ----
// LDS ~45 KiB -> 3 blocks/CU co-resident (12 waves/CU); independent blocks
// overlap ramp/drain. Packed-bf16 z keeps regs ~115 -> no spill at (3,4).
__global__ __launch_bounds__(256) __attribute__((amdgpu_waves_per_eu(3, 4)))
void attn(const float* __restrict__ Q, const short* __restrict__ Khi,
          const float* __restrict__ K, const float* __restrict__ V,
          float* __restrict__ Out) {
  __shared__ short kring[NW][2][2048];         // per-wave 2-slot 4KB-tile ring (32 KiB)
  __shared__ unsigned short Qs[ROWS][136];     // bf16(0.5*Q), A-operand layout
  __shared__ float rbuf[ROWS][64];             // candidate VALUES (then exact)
  __shared__ int   scol[ROWS][64];             // candidate COLUMNS
  __shared__ float exM[NW][ROWS];
  __shared__ int   rcnt[ROWS];
  __shared__ int   rovf[ROWS];                 // per-row overflow flag
  __shared__ float tauB[ROWS], ZB[ROWS];

  const int tid  = threadIdx.x;
  const int lane = tid & 63;
  const int wid  = __builtin_amdgcn_readfirstlane(tid >> 6);  // 0..3
  const int quad = lane >> 4, m16 = lane & 15;
  const int b    = blockIdx.x & 7;             // batch -> XCD pinning
  const int qt   = blockIdx.x >> 3;            // 0..127

  const float* Qb = Q + (size_t)(b * SS + qt * ROWS) * DD;
  const float* Kb = K + (size_t)b * SS * DD;
  const float* Vb = V + (size_t)b * SS * DD;
  float*       Ob = Out + (size_t)(b * SS + qt * ROWS) * DD;
  const short* KHb = Khi + (size_t)b * SS * DD;

  if (tid < ROWS) { rcnt[tid] = 0; rovf[tid] = 0; }

  // ---- stage Q once: bf16(0.5*q), A-operand layout; 8 floats/thread ----
  {
    const int row = tid >> 4, d = (tid & 15) * 8;
    const float4 v0 = *(const float4*)&Qb[row * DD + d];
    const float4 v1 = *(const float4*)&Qb[row * DD + d + 4];
    ushort4 h0, h1;
    h0.x = (unsigned short)f2bf(0.5f * v0.x);
    h0.y = (unsigned short)f2bf(0.5f * v0.y);
    h0.z = (unsigned short)f2bf(0.5f * v0.z);
    h0.w = (unsigned short)f2bf(0.5f * v0.w);
    h1.x = (unsigned short)f2bf(0.5f * v1.x);
    h1.y = (unsigned short)f2bf(0.5f * v1.y);
    h1.z = (unsigned short)f2bf(0.5f * v1.z);
    h1.w = (unsigned short)f2bf(0.5f * v1.w);
    *(ushort4*)&Qs[row][d]     = h0;
    *(ushort4*)&Qs[row][d + 4] = h1;
  }
  __syncthreads();   // also drains vmcnt -> ring counting below starts clean

  bf16x8 qh[4];
#pragma unroll
  for (int s = 0; s < 4; ++s)
    qh[s] = *(const bf16x8*)&Qs[m16][s * 32 + quad * 8];

  // ---- phase 1: z_a = bf16(0.5Q) * Khi^T, 32 tiles/wave, packed-bf16 z ----
  short* ring0 = &kring[wid][0][0];
  short* ring1 = &kring[wid][1][0];
  const short* gw = KHb + ((size_t)(wid * CTW) << 11) + lane * 8;

  stage_tile(gw + 0 * 2048, ring0);
  stage_tile(gw + 1 * 2048, ring1);

  unsigned zpk[CTW][2];                        // packed bf16 z_a, 64 VGPRs
  float mx[4] = {-1e38f, -1e38f, -1e38f, -1e38f};

  sfor<0, CTW>([&](auto ic) {
    constexpr int i = ic.value;
    if constexpr (i < CTW - 1) asm volatile("s_waitcnt vmcnt(4)" ::: "memory");
    else                       asm volatile("s_waitcnt vmcnt(0)" ::: "memory");
    const short* sbl = ((i & 1) ? ring1 : ring0) + lane * 8;
    f32x4 c = {0.f, 0.f, 0.f, 0.f};
    sfor<0, 4>([&](auto sc) {
      constexpr int s = sc.value;
      const bf16x8 bh = *(const bf16x8*)(sbl + (s << 9));
      c = __builtin_amdgcn_mfma_f32_16x16x32_bf16(qh[s], bh, c, 0, 0, 0);
    });
#pragma unroll
    for (int j = 0; j < 4; ++j) mx[j] = fmaxf(mx[j], c[j]);
    zpk[i][0] = pk2(c[0], c[1]);
    zpk[i][1] = pk2(c[2], c[3]);
    if constexpr (i + 2 < CTW) {
      asm volatile("s_waitcnt lgkmcnt(0)" ::: "memory");  // reads retired
      stage_tile(gw + (i + 2) * 2048, (i & 1) ? ring1 : ring0);
    }
  });
  // lane holds packed z_a[row=4*quad+j][col = wid*512 + i*16 + m16]

  // ---- cross-wave row max ----
#pragma unroll
  for (int j = 0; j < 4; ++j)
#pragma unroll
    for (int s = 1; s <= 8; s <<= 1) mx[j] = fmaxf(mx[j], __shfl_xor(mx[j], s));
  if (m16 == 0) {
#pragma unroll
    for (int j = 0; j < 4; ++j) exM[wid][4 * quad + j] = mx[j];
  }
  __syncthreads();
  float M4[4];
#pragma unroll
  for (int j = 0; j < 4; ++j) {
    float m = -1e38f;
#pragma unroll
    for (int w = 0; w < NW; ++w) m = fmaxf(m, exM[w][4 * quad + j]);
    M4[j] = m;
  }

  // ---- compact candidates: z_pk > M - 1.35 (1 + screen err + pack rounding) ----
  sfor<0, CTW>([&](auto cc) {
    constexpr int ct = cc.value;
    const int col = wid * 512 + ct * 16 + m16;
    float v[4];
    v[0] = __uint_as_float(zpk[ct][0] << 16);
    v[1] = __uint_as_float(zpk[ct][0] & 0xffff0000u);
    v[2] = __uint_as_float(zpk[ct][1] << 16);
    v[3] = __uint_as_float(zpk[ct][1] & 0xffff0000u);
#pragma unroll
    for (int j = 0; j < 4; ++j) {
      const int row = 4 * quad + j;
      if (v[j] > M4[j] - 1.35f) {
        const int pos = atomicAdd(&rcnt[row], 1);
        if (pos < 64) { scol[row][pos] = col; rbuf[row][pos] = v[j]; }
        else rovf[row] = 1;
      }
    }
  });
  __syncthreads();   // candidate tables complete

  // ======== wave-local tail: wave wid owns rows 4*wid .. 4*wid+3 ========
  const int rr32 = lane >> 5;
  const int l32  = lane & 31;

#pragma unroll
  for (int p = 0; p < 2; ++p) {
    const int row = 4 * wid + 2 * p + rr32;
    const int nA = rcnt[4 * wid + 2 * p]     < 64 ? rcnt[4 * wid + 2 * p]     : 64;
    const int nB = rcnt[4 * wid + 2 * p + 1] < 64 ? rcnt[4 * wid + 2 * p + 1] : 64;
    const int nr  = rr32 ? nB : nA;
    const int nmx = nA > nB ? nA : nB;

    // ---- refine EXACTLY (2 rows in parallel, 32 lanes each): z = 0.5*dot ----
    {
      const float4 q4 = *(const float4*)&Qb[row * DD + l32 * 4];
      for (int i = 0; i < nmx; ++i) {
        const bool act = i < nr;
        const int c = act ? scol[row][i] : scol[row][0];
        const float4 k4 = *(const float4*)&Kb[(size_t)c * DD + l32 * 4];
        float t = q4.x * k4.x + q4.y * k4.y + q4.z * k4.z + q4.w * k4.w;
#pragma unroll
        for (int s = 1; s <= 16; s <<= 1) t += __shfl_xor(t, s);
        if (act && l32 == 0) rbuf[row][i] = 0.5f * t;
      }
    }
    // rbuf written+read by this same wave only -> no barrier

    // ---- closed-form entmax-1.5 threshold ----
    {
      const float z0 = (l32 < nr)      ? rbuf[row][l32]      : -1e38f;
      const float z1 = (l32 + 32 < nr) ? rbuf[row][l32 + 32] : -1e38f;
      float k0 = 0.f, S10 = 0.f, S20 = 0.f, nb0 = -1e38f;
      float k1 = 0.f, S11 = 0.f, S21 = 0.f, nb1 = -1e38f;
      for (int j = 0; j < nr; ++j) {
        const float w = rbuf[row][j];          // same addr per half -> broadcast
        const bool ge0 = (w > z0) || (w == z0 && j <= l32);
        k0  += ge0 ? 1.f : 0.f;
        S10 += ge0 ? w : 0.f;
        S20  = ge0 ? fmaf(w, w, S20) : S20;
        nb0  = (!ge0 && w > nb0) ? w : nb0;
        const bool ge1 = (w > z1) || (w == z1 && j <= l32 + 32);
        k1  += ge1 ? 1.f : 0.f;
        S11 += ge1 ? w : 0.f;
        S21  = ge1 ? fmaf(w, w, S21) : S21;
        nb1  = (!ge1 && w > nb1) ? w : nb1;
      }
      const float d0 = fmaxf(fmaf(S10, S10, -k0 * (S20 - 1.f)), 0.f);
      const float d1 = fmaxf(fmaf(S11, S11, -k1 * (S21 - 1.f)), 0.f);
      const float tau0 = (S10 - __builtin_sqrtf(d0)) / fmaxf(k0, 1.f);
      const float tau1 = (S11 - __builtin_sqrtf(d1)) / fmaxf(k1, 1.f);
      const bool v0b = z0 > tau0, v1b = z1 > tau1;
      const bool v0  = v0b && (nb0 <= tau0);
      const bool v1  = v1b && (nb1 <= tau1);
      float tv = fmaxf(v0 ? tau0 : -1e38f, v1 ? tau1 : -1e38f);
      float tb = fmaxf(v0b ? tau0 : -1e38f, v1b ? tau1 : -1e38f);
#pragma unroll
      for (int s = 1; s <= 16; s <<= 1) {
        tv = fmaxf(tv, __shfl_xor(tv, s));
        tb = fmaxf(tb, __shfl_xor(tb, s));
      }
      const float tau = (tv > -1e37f) ? tv : tb;           // fp-edge insurance
      const float p0 = fmaxf(z0 - tau, 0.f);
      const float p1 = fmaxf(z1 - tau, 0.f);
      float zp = fmaf(p0, p0, p1 * p1);
#pragma unroll
      for (int s = 1; s <= 16; s <<= 1) zp += __shfl_xor(zp, s);
      if (l32 == 0) { tauB[row] = tau; ZB[row] = zp; }
    }

    // ---- fast output (2 rows in parallel): O = sum p_i * V[col_i] ----
    if (!rovf[row]) {
      const float tau = tauB[row];
      const float iz  = 1.0f / ZB[row];
      float4 o = {0.f, 0.f, 0.f, 0.f};
      for (int i = 0; i < nr; ++i) {
        const float rv = rbuf[row][i];         // same addr per half -> broadcast
        const float tt = fmaxf(rv - tau, 0.f);
        const float pi = tt * tt * iz;
        const int   c  = scol[row][i];
        const float4 v4 = *(const float4*)&Vb[(size_t)c * DD + l32 * 4];
        o.x = fmaf(pi, v4.x, o.x);
        o.y = fmaf(pi, v4.y, o.y);
        o.z = fmaf(pi, v4.z, o.z);
        o.w = fmaf(pi, v4.w, o.w);
      }
      *(float4*)&Ob[row * DD + l32 * 4] = o;
    }
  }

  // ---- exact wave-local dense fallback (candidate overflow; ~unreachable) ----
#pragma unroll
  for (int rr = 0; rr < 4; ++rr) {
    const int frow = 4 * wid + rr;
    if (!rovf[frow]) continue;
    float* zr = (float*)&kring[wid][0][0];     // 8 KB = 2048 f32, wave-private
    for (int c0 = 0; c0 < 32; ++c0) {
      const int c = c0 * 64 + lane;
      const float* kp = &Kb[(size_t)c * DD];
      float t = 0.f;
      for (int d = 0; d < DD; d += 4) {
        const float4 qv = *(const float4*)&Qb[frow * DD + d];
        const float4 kv = *(const float4*)&kp[d];
        t = fmaf(qv.x, kv.x, t); t = fmaf(qv.y, kv.y, t);
        t = fmaf(qv.z, kv.z, t); t = fmaf(qv.w, kv.w, t);
      }
      zr[c] = 0.5f * t;
    }
    float Mr = -1e38f;
    for (int c0 = 0; c0 < 32; ++c0) Mr = fmaxf(Mr, zr[c0 * 64 + lane]);
#pragma unroll
    for (int s = 1; s <= 32; s <<= 1) Mr = fmaxf(Mr, __shfl_xor(Mr, s));
    float tmn = Mr - 1.0f, tmx = Mr - 0.022097086912079608f;
    float tau = 0.5f * (tmn + tmx), Zr = 0.f;
    for (int it = 0; it < 100; ++it) {
      tau = 0.5f * (tmn + tmx);
      float zp = 0.f;
      for (int c0 = 0; c0 < 32; ++c0) {
        const float tt = fmaxf(zr[c0 * 64 + lane] - tau, 0.f);
        zp = fmaf(tt, tt, zp);
      }
#pragma unroll
      for (int s = 1; s <= 32; s <<= 1) zp += __shfl_xor(zp, s);
      Zr = zp;
      const float nmn = (zp >= 1.f) ? tau : tmn;
      const float nmx2 = (zp >= 1.f) ? tmx : tau;
      const bool ch = (nmn != tmn) || (nmx2 != tmx);
      tmn = nmn; tmx = nmx2;
      if (!__any(ch)) break;
    }
    const float iz = 1.0f / Zr;
    float2 o = {0.f, 0.f};
    for (int c = 0; c < SS; ++c) {
      const float tt = fmaxf(zr[c] - tau, 0.f);   // broadcast -> uniform branch
      if (tt > 0.f) {
        const float pi = tt * tt * iz;
        const float2 v2 = *(const float2*)&Vb[(size_t)c * DD + lane * 2];
        o.x = fmaf(pi, v2.x, o.x);
        o.y = fmaf(pi, v2.y, o.y);
      }
    }
    *(float2*)&Ob[frow * DD + lane * 2] = o;
  }
}

extern "C" void kernel_launch(void* const* d_in, const int* in_sizes, int n_in,
                              void* d_out, int out_size, void* d_ws, size_t ws_size,
                              hipStream_t stream) {
  const float* Q = (const float*)d_in[0];
  const float* K = (const float*)d_in[1];
  const float* V = (const float*)d_in[2];
  float* out = (float*)d_out;
  short* Khi = (short*)d_ws;                      // 4 MiB, fragment order

  hipLaunchKernelGGL(ksplit, dim3(BB * SS * DD / (256 * 8)), dim3(256), 0, stream,
                     K, Khi);
  hipLaunchKernelGGL(attn, dim3(BB * (SS / ROWS)), dim3(256), 0, stream,
                     Q, Khi, K, V, out);
}

// Round 14
// 116.771 us; speedup vs baseline: 1.0928x; 1.0928x over previous
//
#include <hip/hip_runtime.h>

#define BB 8
#define SS 2048
#define DD 128
#define ROWS 16            // q rows per block
#define NW 8               // waves per block (512 threads)
#define CTW 16             // col-tiles (of 16) per wave -> 256 cols/wave

typedef short bf16x8 __attribute__((ext_vector_type(8)));
typedef float f32x4 __attribute__((ext_vector_type(4)));

template <int I> struct IC { static constexpr int value = I; };
template <int I, int N, typename F>
__device__ __forceinline__ void sfor(F&& f) {
  if constexpr (I < N) { f(IC<I>{}); sfor<I + 1, N>((F&&)f); }
}

__device__ __forceinline__ short f2bf(float x) {
  return __builtin_bit_cast(short, (__bf16)x);
}

// async DMA one 1KB segment: 64 lanes x 16B, LDS dest = uniform base + lane*16
__device__ __forceinline__ void stage_tile(const short* g, short* l) {
#pragma unroll
  for (int s = 0; s < 4; ++s) {
    __builtin_amdgcn_global_load_lds(
        (const __attribute__((address_space(1))) void*)(g + (s << 9)),
        (__attribute__((address_space(3))) void*)(l + (s << 9)), 16, 0, 0);
  }
}

// ---- prep: Khi = bf16(K) in MFMA B-fragment order; READ-COALESCED ----
__global__ __launch_bounds__(256)
void ksplit(const float* __restrict__ K, short* __restrict__ Khi) {
  const int lin = blockIdx.x * 256 + threadIdx.x;    // 262144 chunks of 8
  const int r   = lin >> 4;                          // global K row (b*2048+row)
  const int c8  = lin & 15;                          // which 8-float chunk
  const float4 v0 = *(const float4*)(K + (size_t)lin * 8);
  const float4 v1 = *(const float4*)(K + (size_t)lin * 8 + 4);
  bf16x8 h;
  h[0] = f2bf(v0.x); h[1] = f2bf(v0.y); h[2] = f2bf(v0.z); h[3] = f2bf(v0.w);
  h[4] = f2bf(v1.x); h[5] = f2bf(v1.y); h[6] = f2bf(v1.z); h[7] = f2bf(v1.w);
  const int bct  = r >> 4;                           // b*128 + ct
  const int m16  = r & 15;
  const int s    = c8 >> 2;
  const int quad = c8 & 3;
  const size_t out = ((((size_t)bct * 4 + s) * 64) + quad * 16 + m16) * 8;
  *(bf16x8*)(Khi + out) = h;
}

// ---- fused entmax attention: R8 (best measured) ----
__global__ __launch_bounds__(512) __attribute__((amdgpu_waves_per_eu(3, 4)))
void attn(const float* __restrict__ Q, const short* __restrict__ Khi,
          const float* __restrict__ K, const float* __restrict__ V,
          float* __restrict__ Out) {
  __shared__ short kring[NW][2][2048];         // per-wave 2-slot 4KB-tile ring (64 KiB)
  __shared__ unsigned short Qs[ROWS][136];     // bf16(0.5*Q), A-operand layout
  __shared__ float rbuf[ROWS][64];             // candidate VALUES (then exact)
  __shared__ int   scol[ROWS][64];             // candidate COLUMNS
  __shared__ float exM[NW][ROWS];
  __shared__ int   rcnt[ROWS];
  __shared__ int   rovf[ROWS];                 // per-row overflow flag
  __shared__ float tauB[ROWS], ZB[ROWS];

  const int tid  = threadIdx.x;
  const int lane = tid & 63;
  const int wid  = __builtin_amdgcn_readfirstlane(tid >> 6);  // 0..7
  const int quad = lane >> 4, m16 = lane & 15;
  const int b    = blockIdx.x & 7;             // batch -> XCD pinning
  const int qt   = blockIdx.x >> 3;            // 0..127

  const float* Qb = Q + (size_t)(b * SS + qt * ROWS) * DD;
  const float* Kb = K + (size_t)b * SS * DD;
  const float* Vb = V + (size_t)b * SS * DD;
  float*       Ob = Out + (size_t)(b * SS + qt * ROWS) * DD;
  const short* KHb = Khi + (size_t)b * SS * DD;

  if (tid < ROWS) { rcnt[tid] = 0; rovf[tid] = 0; }

  // ---- stage Q once: bf16(0.5*q), A-operand layout ----
  {
    const int row = tid >> 5, d = (tid & 31) * 4;
    const float4 v = *(const float4*)&Qb[row * DD + d];
    ushort4 h;
    h.x = (unsigned short)f2bf(0.5f * v.x);
    h.y = (unsigned short)f2bf(0.5f * v.y);
    h.z = (unsigned short)f2bf(0.5f * v.z);
    h.w = (unsigned short)f2bf(0.5f * v.w);
    *(ushort4*)&Qs[row][d] = h;
  }
  __syncthreads();   // also drains vmcnt -> ring counting below starts clean

  bf16x8 qh[4];
#pragma unroll
  for (int s = 0; s < 4; ++s)
    qh[s] = *(const bf16x8*)&Qs[m16][s * 32 + quad * 8];

  // ---- phase 1: z_a = bf16(0.5Q) * Khi^T via per-wave async LDS ring ----
  short* ring0 = &kring[wid][0][0];
  short* ring1 = &kring[wid][1][0];
  const short* gw = KHb + ((size_t)(wid * CTW) << 11) + lane * 8;

  stage_tile(gw + 0 * 2048, ring0);
  stage_tile(gw + 1 * 2048, ring1);

  f32x4 acc[CTW];
  sfor<0, CTW>([&](auto ic) {
    constexpr int i = ic.value;
    if constexpr (i < CTW - 1) asm volatile("s_waitcnt vmcnt(4)" ::: "memory");
    else                       asm volatile("s_waitcnt vmcnt(0)" ::: "memory");
    const short* sbl = ((i & 1) ? ring1 : ring0) + lane * 8;
    f32x4 c = {0.f, 0.f, 0.f, 0.f};
    sfor<0, 4>([&](auto sc) {
      constexpr int s = sc.value;
      const bf16x8 bh = *(const bf16x8*)(sbl + (s << 9));
      c = __builtin_amdgcn_mfma_f32_16x16x32_bf16(qh[s], bh, c, 0, 0, 0);
    });
    acc[i] = c;
    if constexpr (i + 2 < CTW) {
      asm volatile("s_waitcnt lgkmcnt(0)" ::: "memory");  // reads retired
      stage_tile(gw + (i + 2) * 2048, (i & 1) ? ring1 : ring0);
    }
  });

  // ---- row max of z_a ----
  float mx[4] = {-1e38f, -1e38f, -1e38f, -1e38f};
  sfor<0, CTW>([&](auto ic) {
#pragma unroll
    for (int j = 0; j < 4; ++j) mx[j] = fmaxf(mx[j], acc[ic.value][j]);
  });
#pragma unroll
  for (int j = 0; j < 4; ++j)
#pragma unroll
    for (int s = 1; s <= 8; s <<= 1) mx[j] = fmaxf(mx[j], __shfl_xor(mx[j], s));
  if (m16 == 0) {
#pragma unroll
    for (int j = 0; j < 4; ++j) exM[wid][4 * quad + j] = mx[j];
  }
  __syncthreads();
  float M4[4];
#pragma unroll
  for (int j = 0; j < 4; ++j) {
    float m = -1e38f;
#pragma unroll
    for (int w = 0; w < NW; ++w) m = fmaxf(m, exM[w][4 * quad + j]);
    M4[j] = m;
  }

  // ---- compact candidates: z_a > M - 1.25 (margin = 1 + ~13 sigma of z_a err) ----
  sfor<0, CTW>([&](auto ic) {
    constexpr int i = ic.value;
    const int col = wid * 256 + i * 16 + m16;
#pragma unroll
    for (int j = 0; j < 4; ++j) {
      const int row = 4 * quad + j;
      if (acc[i][j] > M4[j] - 1.25f) {
        const int pos = atomicAdd(&rcnt[row], 1);
        if (pos < 64) { scol[row][pos] = col; rbuf[row][pos] = acc[i][j]; }
        else rovf[row] = 1;
      }
    }
  });
  __syncthreads();   // candidate tables complete; acc dead from here

  // ======== wave-local tail: wave wid owns rows 2*wid, 2*wid+1 ========
  const int rr32 = lane >> 5;                  // which of this wave's rows
  const int row  = 2 * wid + rr32;
  const int l32  = lane & 31;
  const int nA = rcnt[2 * wid]     < 64 ? rcnt[2 * wid]     : 64;
  const int nB = rcnt[2 * wid + 1] < 64 ? rcnt[2 * wid + 1] : 64;
  const int nr  = rr32 ? nB : nA;
  const int nmx = nA > nB ? nA : nB;

  // ---- refine EXACTLY (2 rows in parallel, 32 lanes each): z = 0.5*dot ----
  {
    const float4 q4 = *(const float4*)&Qb[row * DD + l32 * 4];
    for (int i = 0; i < nmx; ++i) {
      const bool act = i < nr;
      const int c = act ? scol[row][i] : scol[row][0];
      const float4 k4 = *(const float4*)&Kb[(size_t)c * DD + l32 * 4];
      float t = q4.x * k4.x + q4.y * k4.y + q4.z * k4.z + q4.w * k4.w;
#pragma unroll
      for (int s = 1; s <= 16; s <<= 1) t += __shfl_xor(t, s);
      if (act && l32 == 0) rbuf[row][i] = 0.5f * t;
    }
  }
  // rbuf written+read by this same wave only -> no barrier

  // ---- closed-form entmax-1.5 threshold ----
  // For support size k: tau_k = (S1k - sqrt(S1k^2 - k(S2k-1)))/k; valid iff
  // z_(k) > tau_k >= z_(k+1). Each lane tests its own candidate(s) as the
  // minimum support element via one LDS-broadcast pass (no sort).
  {
    const float z0 = (l32 < nr)      ? rbuf[row][l32]      : -1e38f;
    const float z1 = (l32 + 32 < nr) ? rbuf[row][l32 + 32] : -1e38f;
    float k0 = 0.f, S10 = 0.f, S20 = 0.f, nb0 = -1e38f;
    float k1 = 0.f, S11 = 0.f, S21 = 0.f, nb1 = -1e38f;
    for (int j = 0; j < nr; ++j) {
      const float w = rbuf[row][j];            // same addr per half -> broadcast
      // total order: value desc, slot index asc (slot of z0 is l32, z1 is l32+32)
      const bool ge0 = (w > z0) || (w == z0 && j <= l32);
      k0  += ge0 ? 1.f : 0.f;
      S10 += ge0 ? w : 0.f;
      S20  = ge0 ? fmaf(w, w, S20) : S20;
      nb0  = (!ge0 && w > nb0) ? w : nb0;
      const bool ge1 = (w > z1) || (w == z1 && j <= l32 + 32);
      k1  += ge1 ? 1.f : 0.f;
      S11 += ge1 ? w : 0.f;
      S21  = ge1 ? fmaf(w, w, S21) : S21;
      nb1  = (!ge1 && w > nb1) ? w : nb1;
    }
    const float d0 = fmaxf(fmaf(S10, S10, -k0 * (S20 - 1.f)), 0.f);
    const float d1 = fmaxf(fmaf(S11, S11, -k1 * (S21 - 1.f)), 0.f);
    const float tau0 = (S10 - __builtin_sqrtf(d0)) / fmaxf(k0, 1.f);
    const float tau1 = (S11 - __builtin_sqrtf(d1)) / fmaxf(k1, 1.f);
    const bool v0b = z0 > tau0, v1b = z1 > tau1;           // necessary cond
    const bool v0  = v0b && (nb0 <= tau0);                 // full support cond
    const bool v1  = v1b && (nb1 <= tau1);
    float tv = fmaxf(v0 ? tau0 : -1e38f, v1 ? tau1 : -1e38f);
    float tb = fmaxf(v0b ? tau0 : -1e38f, v1b ? tau1 : -1e38f);
#pragma unroll
    for (int s = 1; s <= 16; s <<= 1) {
      tv = fmaxf(tv, __shfl_xor(tv, s));
      tb = fmaxf(tb, __shfl_xor(tb, s));
    }
    const float tau = (tv > -1e37f) ? tv : tb;             // fp-edge insurance
    const float p0 = fmaxf(z0 - tau, 0.f);
    const float p1 = fmaxf(z1 - tau, 0.f);
    float zp = fmaf(p0, p0, p1 * p1);
#pragma unroll
    for (int s = 1; s <= 16; s <<= 1) zp += __shfl_xor(zp, s);
    if (l32 == 0) { tauB[row] = tau; ZB[row] = zp; }
  }

  // ---- fast output (2 rows in parallel): O = sum p_i * V[col_i] ----
  if (!rovf[row]) {
    const float tau = tauB[row];
    const float iz  = 1.0f / ZB[row];
    float4 o = {0.f, 0.f, 0.f, 0.f};
    for (int i = 0; i < nr; ++i) {
      const float rv = rbuf[row][i];           // same addr per half -> broadcast
      const float tt = fmaxf(rv - tau, 0.f);
      const float pi = tt * tt * iz;
      const int   c  = scol[row][i];
      const float4 v4 = *(const float4*)&Vb[(size_t)c * DD + l32 * 4];
      o.x = fmaf(pi, v4.x, o.x);
      o.y = fmaf(pi, v4.y, o.y);
      o.z = fmaf(pi, v4.z, o.z);
      o.w = fmaf(pi, v4.w, o.w);
    }
    *(float4*)&Ob[row * DD + l32 * 4] = o;
  }

  // ---- exact wave-local dense fallback (candidate overflow; ~unreachable) ----
#pragma unroll
  for (int rr = 0; rr < 2; ++rr) {
    const int frow = 2 * wid + rr;
    if (!rovf[frow]) continue;
    float* zr = (float*)&kring[wid][0][0];     // 8 KB = 2048 f32, wave-private
    for (int c0 = 0; c0 < 32; ++c0) {
      const int c = c0 * 64 + lane;
      const float* kp = &Kb[(size_t)c * DD];
      float t = 0.f;
      for (int d = 0; d < DD; d += 4) {
        const float4 qv = *(const float4*)&Qb[frow * DD + d];
        const float4 kv = *(const float4*)&kp[d];
        t = fmaf(qv.x, kv.x, t); t = fmaf(qv.y, kv.y, t);
        t = fmaf(qv.z, kv.z, t); t = fmaf(qv.w, kv.w, t);
      }
      zr[c] = 0.5f * t;
    }
    float Mr = -1e38f;
    for (int c0 = 0; c0 < 32; ++c0) Mr = fmaxf(Mr, zr[c0 * 64 + lane]);
#pragma unroll
    for (int s = 1; s <= 32; s <<= 1) Mr = fmaxf(Mr, __shfl_xor(Mr, s));
    float tmn = Mr - 1.0f, tmx = Mr - 0.022097086912079608f;
    float tau = 0.5f * (tmn + tmx), Zr = 0.f;
    for (int it = 0; it < 100; ++it) {
      tau = 0.5f * (tmn + tmx);
      float zp = 0.f;
      for (int c0 = 0; c0 < 32; ++c0) {
        const float tt = fmaxf(zr[c0 * 64 + lane] - tau, 0.f);
        zp = fmaf(tt, tt, zp);
      }
#pragma unroll
      for (int s = 1; s <= 32; s <<= 1) zp += __shfl_xor(zp, s);
      Zr = zp;
      const float nmn = (zp >= 1.f) ? tau : tmn;
      const float nmx2 = (zp >= 1.f) ? tmx : tau;
      const bool ch = (nmn != tmn) || (nmx2 != tmx);
      tmn = nmn; tmx = nmx2;
      if (!__any(ch)) break;
    }
    const float iz = 1.0f / Zr;
    float2 o = {0.f, 0.f};
    for (int c = 0; c < SS; ++c) {
      const float tt = fmaxf(zr[c] - tau, 0.f);   // broadcast -> uniform branch
      if (tt > 0.f) {
        const float pi = tt * tt * iz;
        const float2 v2 = *(const float2*)&Vb[(size_t)c * DD + lane * 2];
        o.x = fmaf(pi, v2.x, o.x);
        o.y = fmaf(pi, v2.y, o.y);
      }
    }
    *(float2*)&Ob[frow * DD + lane * 2] = o;
  }
}

extern "C" void kernel_launch(void* const* d_in, const int* in_sizes, int n_in,
                              void* d_out, int out_size, void* d_ws, size_t ws_size,
                              hipStream_t stream) {
  const float* Q = (const float*)d_in[0];
  const float* K = (const float*)d_in[1];
  const float* V = (const float*)d_in[2];
  float* out = (float*)d_out;
  short* Khi = (short*)d_ws;                      // 4 MiB, fragment order

  hipLaunchKernelGGL(ksplit, dim3(BB * SS * DD / (256 * 8)), dim3(256), 0, stream,
                     K, Khi);
  hipLaunchKernelGGL(attn, dim3(BB * (SS / ROWS)), dim3(512), 0, stream,
                     Q, Khi, K, V, out);
}